// Round 1
// baseline (780.463 us; speedup 1.0000x reference)
//
#include <hip/hip_runtime.h>

// Problem constants (derived from in_sizes at launch, these are for reference):
//   N_NODES=100000, N_EDGES=800000, D_EDGE=64, D_NODE=128, D_IN=256, D_OUT=128

#define EDGES_PER_WAVE 8
#define NB 32  // nodes per block in the GEMM kernel

// ---------------------------------------------------------------------------
// Scatter: agg[recv[e]][f] += edata[e][f].  One wave = 64 lanes = 64 features.
// Each wave handles EDGES_PER_WAVE edges: prefetch all loads, then issue
// fire-and-forget coalesced atomics (256 B per edge per wave).
// ---------------------------------------------------------------------------
__global__ __launch_bounds__(256) void scatter_kernel(
    const float* __restrict__ edata, const int* __restrict__ recv,
    float* __restrict__ agg, int n_edges) {
  const int lane = threadIdx.x & 63;
  const int wave = blockIdx.x * (blockDim.x >> 6) + (threadIdx.x >> 6);
  const int e0 = wave * EDGES_PER_WAVE;

  if (e0 + EDGES_PER_WAVE <= n_edges) {
    int r[EDGES_PER_WAVE];
    float v[EDGES_PER_WAVE];
#pragma unroll
    for (int i = 0; i < EDGES_PER_WAVE; ++i) {
      const int e = e0 + i;
      r[i] = recv[e];
      v[i] = edata[(size_t)e * 64 + lane];
    }
#pragma unroll
    for (int i = 0; i < EDGES_PER_WAVE; ++i) {
      atomicAdd(&agg[(size_t)r[i] * 64 + lane], v[i]);
    }
  } else {
    for (int e = e0; e < n_edges; ++e) {
      const int r = recv[e];
      const float v = edata[(size_t)e * 64 + lane];
      atomicAdd(&agg[(size_t)r * 64 + lane], v);
    }
  }
}

// ---------------------------------------------------------------------------
// Fused concat + GEMM + bias:
//   out[n, :] = [agg_a[n] | agg_b[n] | vdata[n]] @ W + b
// Block = 256 threads, handles NB=32 nodes. x rows staged in LDS
// (row stride 260 floats: conflict-free staging writes, 16B-aligned b128
// compute reads, 2-address broadcast per wave = free).
// Thread t: cols 4*(t&31)..+3, nodes (t>>5)*4..+3 -> 16 fp32 accumulators.
// ---------------------------------------------------------------------------
__device__ __forceinline__ void fma4(float4& acc, float s, const float4& w) {
  acc.x = fmaf(s, w.x, acc.x);
  acc.y = fmaf(s, w.y, acc.y);
  acc.z = fmaf(s, w.z, acc.z);
  acc.w = fmaf(s, w.w, acc.w);
}

__global__ __launch_bounds__(256) void fused_gemm_kernel(
    const float* __restrict__ agg_a, const float* __restrict__ agg_b,
    const float* __restrict__ vdata, const float* __restrict__ W,
    const float* __restrict__ bias, float* __restrict__ out, int n_nodes) {
  __shared__ float xs[NB][260];

  const int tid = threadIdx.x;
  const int n0 = blockIdx.x * NB;

  // ---- stage x = [agg_a | agg_b | vdata] for NB nodes into LDS ----
  const float4* A4 = (const float4*)(agg_a + (size_t)n0 * 64);
  const float4* B4 = (const float4*)(agg_b + (size_t)n0 * 64);
  const float4* V4 = (const float4*)(vdata + (size_t)n0 * 128);
#pragma unroll
  for (int i = tid; i < NB * 16; i += 256) {  // 512 float4 each for agg_a/agg_b
    const int node = i >> 4;
    const int kk = (i & 15) << 2;
    *(float4*)&xs[node][kk] = A4[i];
    *(float4*)&xs[node][64 + kk] = B4[i];
  }
#pragma unroll
  for (int i = tid; i < NB * 32; i += 256) {  // 1024 float4 for vdata
    const int node = i >> 5;
    const int kk = (i & 31) << 2;
    *(float4*)&xs[node][128 + kk] = V4[i];
  }
  __syncthreads();

  const int c = tid & 31;      // float4 column index (cols 4c..4c+3)
  const int nset = tid >> 5;   // node group: nodes nset*4 .. nset*4+3
  const float4* W4 = (const float4*)W;

  float4 acc0 = {0.f, 0.f, 0.f, 0.f};
  float4 acc1 = acc0, acc2 = acc0, acc3 = acc0;

#pragma unroll 4
  for (int k = 0; k < 256; k += 4) {
    const float4 w0 = W4[(k + 0) * 32 + c];
    const float4 w1 = W4[(k + 1) * 32 + c];
    const float4 w2 = W4[(k + 2) * 32 + c];
    const float4 w3 = W4[(k + 3) * 32 + c];
    const float4 x0 = *(const float4*)&xs[nset * 4 + 0][k];
    const float4 x1 = *(const float4*)&xs[nset * 4 + 1][k];
    const float4 x2 = *(const float4*)&xs[nset * 4 + 2][k];
    const float4 x3 = *(const float4*)&xs[nset * 4 + 3][k];

    fma4(acc0, x0.x, w0); fma4(acc0, x0.y, w1); fma4(acc0, x0.z, w2); fma4(acc0, x0.w, w3);
    fma4(acc1, x1.x, w0); fma4(acc1, x1.y, w1); fma4(acc1, x1.z, w2); fma4(acc1, x1.w, w3);
    fma4(acc2, x2.x, w0); fma4(acc2, x2.y, w1); fma4(acc2, x2.z, w2); fma4(acc2, x2.w, w3);
    fma4(acc3, x3.x, w0); fma4(acc3, x3.y, w1); fma4(acc3, x3.z, w2); fma4(acc3, x3.w, w3);
  }

  // ---- epilogue: bias + store ----
  const float4 bb = ((const float4*)bias)[c];
  acc0.x += bb.x; acc0.y += bb.y; acc0.z += bb.z; acc0.w += bb.w;
  acc1.x += bb.x; acc1.y += bb.y; acc1.z += bb.z; acc1.w += bb.w;
  acc2.x += bb.x; acc2.y += bb.y; acc2.z += bb.z; acc2.w += bb.w;
  acc3.x += bb.x; acc3.y += bb.y; acc3.z += bb.z; acc3.w += bb.w;

  float4* O4 = (float4*)out;
  const int nb = n0 + nset * 4;
  if (nb + 3 < n_nodes) {
    O4[(size_t)(nb + 0) * 32 + c] = acc0;
    O4[(size_t)(nb + 1) * 32 + c] = acc1;
    O4[(size_t)(nb + 2) * 32 + c] = acc2;
    O4[(size_t)(nb + 3) * 32 + c] = acc3;
  } else {
    if (nb + 0 < n_nodes) O4[(size_t)(nb + 0) * 32 + c] = acc0;
    if (nb + 1 < n_nodes) O4[(size_t)(nb + 1) * 32 + c] = acc1;
    if (nb + 2 < n_nodes) O4[(size_t)(nb + 2) * 32 + c] = acc2;
    if (nb + 3 < n_nodes) O4[(size_t)(nb + 3) * 32 + c] = acc3;
  }
}

// ---------------------------------------------------------------------------
// Launch
// ---------------------------------------------------------------------------
extern "C" void kernel_launch(void* const* d_in, const int* in_sizes, int n_in,
                              void* d_out, int out_size, void* d_ws, size_t ws_size,
                              hipStream_t stream) {
  const float* vdata   = (const float*)d_in[0];
  const float* edata_a = (const float*)d_in[1];
  const float* edata_b = (const float*)d_in[2];
  const int*   conn_a  = (const int*)d_in[3];  // [2, E] int32 (JAX canonicalizes int64->int32)
  const int*   conn_b  = (const int*)d_in[4];
  const float* W       = (const float*)d_in[5];
  const float* bias    = (const float*)d_in[6];
  float*       out     = (float*)d_out;

  const int n_nodes = in_sizes[0] / 128;  // 100000
  const int n_edges = in_sizes[1] / 64;   // 800000

  float* agg_a = (float*)d_ws;
  float* agg_b = agg_a + (size_t)n_nodes * 64;

  // agg buffers must be zeroed every call (ws is poisoned to 0xAA).
  hipMemsetAsync(d_ws, 0, (size_t)n_nodes * 64 * 2 * sizeof(float), stream);

  const int waves = (n_edges + EDGES_PER_WAVE - 1) / EDGES_PER_WAVE;
  const int sblocks = (waves + 3) / 4;  // 4 waves per 256-thread block
  scatter_kernel<<<sblocks, 256, 0, stream>>>(edata_a, conn_a + n_edges, agg_a, n_edges);
  scatter_kernel<<<sblocks, 256, 0, stream>>>(edata_b, conn_b + n_edges, agg_b, n_edges);

  const int gblocks = (n_nodes + NB - 1) / NB;  // 3125
  fused_gemm_kernel<<<gblocks, 256, 0, stream>>>(agg_a, agg_b, vdata, W, bias, out, n_nodes);
}